// Round 10
// baseline (205.714 us; speedup 1.0000x reference)
//
#include <hip/hip_runtime.h>
#include <hip/hip_bf16.h>
#include <stdint.h>

#define BATCH 32
#define CIN   256
#define COUT  256
#define HW    3136   // 56*56
#define NPAD  3200   // pad HW to multiple of 128

#define AS1 __attribute__((address_space(1)))
#define AS3 __attribute__((address_space(3)))

typedef short bf16x8 __attribute__((ext_vector_type(8)));
typedef float f32x4  __attribute__((ext_vector_type(4)));

__device__ __forceinline__ unsigned short f2bf(float f) {
    unsigned u = __float_as_uint(f);
    u += 0x7fffu + ((u >> 16) & 1u);   // round-to-nearest-even
    return (unsigned short)(u >> 16);
}

// ---------------- K0: fold BN2 into pw weights; zero pwmax -----------------
__global__ __launch_bounds__(256) void prep_kernel(
        const float* __restrict__ pw_w, const float* __restrict__ pw_b,
        const float* __restrict__ g2, const float* __restrict__ be2,
        const float* __restrict__ mu2, const float* __restrict__ va2,
        unsigned short* __restrict__ Wp, float* __restrict__ b2,
        unsigned* __restrict__ pwmax) {
    int o = blockIdx.x;
    int t = threadIdx.x;
    float inv2 = g2[o] * rsqrtf(va2[o] + 1e-5f);
    Wp[o * CIN + t] = f2bf(pw_w[o * CIN + t] * inv2);
    if (t == 0) b2[o] = pw_b[o] * inv2 + be2[o] - mu2[o] * inv2;
    int idx = blockIdx.x * 256 + t;
    if (idx < BATCH * COUT) pwmax[idx] = 0u;
}

// ---------------- K1: depthwise 3x3 + BN1 + ReLU + SELF-CUT -> y bf16 -----
__global__ __launch_bounds__(256) void dw_kernel(
        const float* __restrict__ x, const float* __restrict__ dww,
        const float* __restrict__ dwb,
        const float* __restrict__ g1, const float* __restrict__ be1,
        const float* __restrict__ mu1, const float* __restrict__ va1,
        unsigned short* __restrict__ y) {
    __shared__ float xs[4 * 3136];
    int tid  = threadIdx.x;
    int lane = tid & 63, wid = tid >> 6;
    int plane = blockIdx.x * 4 + wid;
    int c = plane & 255;

    const float* xp = x + (size_t)plane * HW;
    float* xw = xs + wid * 3136;

#pragma unroll
    for (int i = 0; i < 12; ++i)
        __builtin_amdgcn_global_load_lds(
            (const AS1 void*)(xp + i * 256 + lane * 4),
            (AS3 void*)(xw + i * 256), 16, 0, 0);
    __builtin_amdgcn_global_load_lds(
        (const AS1 void*)(xp + 3072 + lane),
        (AS3 void*)(xw + 3072), 4, 0, 0);

    float w00 = dww[c*9+0], w01 = dww[c*9+1], w02 = dww[c*9+2];
    float w10 = dww[c*9+3], w11 = dww[c*9+4], w12 = dww[c*9+5];
    float w20 = dww[c*9+6], w21 = dww[c*9+7], w22 = dww[c*9+8];
    float inv = g1[c] * rsqrtf(va1[c] + 1e-5f);
    float b0  = dwb[c] * inv + (be1[c] - mu1[c] * inv);

    int  col    = lane < 56 ? lane : 55;
    bool active = lane < 56;
    if (lane == 0)  { w00 = 0.f; w10 = 0.f; w20 = 0.f; }
    if (lane >= 55) { w02 = 0.f; w12 = 0.f; w22 = 0.f; }
    int il = (lane == 0) ? 0 : col - 1;
    int ir = (col == 55) ? 55 : col + 1;

    asm volatile("s_waitcnt vmcnt(0)" ::: "memory");
    __builtin_amdgcn_sched_barrier(0);

    const float* xb = xw;
    unsigned short* yp = y + (size_t)plane * NPAD + col;

    float A = 0.f;
    float Bv = 0.f;
    float lmax = 0.f;
#pragma unroll
    for (int q = 0; q < 56; q += 2) {
        float l0 = xb[q*56 + il],      c0 = xb[q*56 + col],      r0 = xb[q*56 + ir];
        float l1 = xb[(q+1)*56 + il],  c1 = xb[(q+1)*56 + col],  r1 = xb[(q+1)*56 + ir];
        if (q > 0) {
            float o0 = fmaf(l0, w20, fmaf(c0, w21, fmaf(r0, w22, A)));
            float v = fmaxf(fmaf(o0, inv, b0), 0.f);
            if (active) { lmax = fmaxf(lmax, v); yp[(q-1)*56] = f2bf(v); }
        }
        {
            float o1 = fmaf(l0, w10, fmaf(c0, w11, fmaf(r0, w12,
                       fmaf(l1, w20, fmaf(c1, w21, fmaf(r1, w22, Bv))))));
            float v = fmaxf(fmaf(o1, inv, b0), 0.f);
            if (active) { lmax = fmaxf(lmax, v); yp[q*56] = f2bf(v); }
        }
        float top0 = fmaf(l0, w00, fmaf(c0, w01, r0 * w02));
        A  = fmaf(l1, w10, fmaf(c1, w11, fmaf(r1, w12, top0)));
        Bv = fmaf(l1, w00, fmaf(c1, w01, r1 * w02));
    }
    {
        float v = fmaxf(fmaf(A, inv, b0), 0.f);
        if (active) { lmax = fmaxf(lmax, v); yp[55*56] = f2bf(v); }
    }
    for (int off = 32; off >= 1; off >>= 1)
        lmax = fmaxf(lmax, __shfl_xor(lmax, off, 64));
    if (lane < 8) *(uint4*)(y + (size_t)plane * NPAD + HW + lane * 8)
        = make_uint4(0, 0, 0, 0);
    if (lmax < 4.0f) {
        asm volatile("s_waitcnt vmcnt(0)" ::: "memory");
        unsigned short* yp0 = y + (size_t)plane * NPAD;
#pragma unroll
        for (int it = 0; it < 7; ++it) {
            int idx = it * 64 + lane;
            if (idx < 392) *(uint4*)(yp0 + idx * 8) = make_uint4(0, 0, 0, 0);
        }
    }
}

// ---------------- K2 helpers ----------------------------------------------
__device__ __forceinline__ void load_raw(uint2* dst, const unsigned short* bsrc, int kk) {
#pragma unroll
    for (int r = 0; r < 4; ++r)
        dst[r] = *(const uint2*)(bsrc + (size_t)(kk * 64 + r) * NPAD);
}

__device__ __forceinline__ void pack_b(const uint2* src, char* dstbase,
                                       const int* sb_) {
    uint2 r0 = src[0], r1 = src[1], r2 = src[2], r3 = src[3];
#pragma unroll
    for (int i2 = 0; i2 < 4; ++i2) {
        unsigned x0 = (i2 & 2) ? r0.y : r0.x;
        unsigned x1 = (i2 & 2) ? r1.y : r1.x;
        unsigned x2 = (i2 & 2) ? r2.y : r2.x;
        unsigned x3 = (i2 & 2) ? r3.y : r3.x;
        if (i2 & 1) { x0 >>= 16; x2 >>= 16; }
        else        { x0 &= 0xffffu; x2 &= 0xffffu; }
        unsigned px = (i2 & 1) ? (x0 | (x1 & 0xffff0000u)) : (x0 | (x1 << 16));
        unsigned py = (i2 & 1) ? (x2 | (x3 & 0xffff0000u)) : (x2 | (x3 << 16));
        *(uint2*)(dstbase + sb_[i2]) = make_uint2(px, py);
    }
}

__device__ __forceinline__ void read_af(bf16x8* af, const char* Al,
                                        int wm, int l15, int l4) {
#pragma unroll
    for (int h = 0; h < 2; ++h)
#pragma unroll
        for (int mf = 0; mf < 4; ++mf) {
            int m = wm + mf * 16 + l15;
            int cc = h * 4 + l4;
            af[h * 4 + mf] = *(const bf16x8*)(Al + m * 128 + ((cc ^ (m & 7)) << 4));
        }
}

__device__ __forceinline__ void do_mfma(f32x4 (*acc)[4], const bf16x8* af,
                                        const char* Blb, int wn, int l15, int l4) {
#pragma unroll
    for (int h = 0; h < 2; ++h) {
        bf16x8 bfr[4];
        int cc = h * 4 + l4;
#pragma unroll
        for (int nf = 0; nf < 4; ++nf) {
            int n = wn + nf * 16 + l15;
            bfr[nf] = *(const bf16x8*)(Blb + n * 128 + ((cc ^ ((n >> 2) & 7)) << 4));
        }
#pragma unroll
        for (int mf = 0; mf < 4; ++mf)
#pragma unroll
            for (int nf = 0; nf < 4; ++nf)
                acc[mf][nf] = __builtin_amdgcn_mfma_f32_16x16x32_bf16(
                    af[h * 4 + mf], bfr[nf], acc[mf][nf], 0, 0, 0);
    }
}

__device__ __forceinline__ void sink_af(const bf16x8* af, unsigned &lv) {
#pragma unroll
    for (int i = 0; i < 8; ++i) {
        uint4 u = __builtin_bit_cast(uint4, af[i]);
        lv ^= u.x ^ u.y ^ u.z ^ u.w;
    }
}

__device__ __forceinline__ void sink_b(const char* Blb, int wn, int l15, int l4,
                                       unsigned &lv) {
#pragma unroll
    for (int h = 0; h < 2; ++h) {
        int cc = h * 4 + l4;
#pragma unroll
        for (int nf = 0; nf < 4; ++nf) {
            int n = wn + nf * 16 + l15;
            bf16x8 bb = *(const bf16x8*)(Blb + n * 128 + ((cc ^ ((n >> 2) & 7)) << 4));
            uint4 u = __builtin_bit_cast(uint4, bb);
            lv ^= u.x ^ u.y ^ u.z ^ u.w;
        }
    }
}

#define WAIT_V0_BAR  { asm volatile("s_waitcnt vmcnt(0)" ::: "memory");   \
                       __builtin_amdgcn_sched_barrier(0);                  \
                       __builtin_amdgcn_s_barrier();                       \
                       __builtin_amdgcn_sched_barrier(0); }
#define WAIT_LG_BAR  { asm volatile("s_waitcnt lgkmcnt(0)" ::: "memory"); \
                       __builtin_amdgcn_sched_barrier(0);                  \
                       __builtin_amdgcn_s_barrier();                       \
                       __builtin_amdgcn_sched_barrier(0); }

// ---------------- K2: pointwise GEMM (R8 baseline, unchanged) --------------
__global__ __launch_bounds__(512, 2) void pw_kernel(
        const unsigned short* __restrict__ y, const unsigned short* __restrict__ Wp,
        const float* __restrict__ b2, float* __restrict__ z,
        unsigned* __restrict__ pwmax) {
    __shared__ __align__(16) char lds[65536];
    char* Al  = lds;
    char* Bl0 = lds + 32768;
    char* Bl1 = lds + 49152;

    int bid0 = blockIdx.x;                      // 800
    int bid = (bid0 & 7) * 100 + (bid0 >> 3);
    int b = bid / 25, nt = bid % 25;
    int n0 = nt * 128;

    int tid = threadIdx.x;
    int lane = tid & 63, wid = tid >> 6;
    int wm = (wid >> 1) * 64, wn = (wid & 1) * 64;
    int l15 = lane & 15, l4 = lane >> 4;

    const unsigned short* yb = y + (size_t)b * CIN * NPAD;

    const unsigned short* agsrc[4];
    int aoff[4];
#pragma unroll
    for (int i = 0; i < 4; ++i) {
        int s = i * 512 + tid;
        int m = s >> 3, cch = s & 7, dch = cch ^ (m & 7);
        agsrc[i] = Wp + m * 256 + dch * 8;
        aoff[i] = i * 8192 + wid * 1024;
    }
    int q = tid >> 5, nq = tid & 31;
    const unsigned short* bsrc = yb + q * 4 * NPAD + n0 + nq * 4;
    int sb_[4];
#pragma unroll
    for (int i2 = 0; i2 < 4; ++i2) {
        int nloc = nq * 4 + i2;
        sb_[i2] = nloc * 128 + (((q >> 1) ^ ((nloc >> 2) & 7)) << 4) + ((q & 1) << 3);
    }

    f32x4 acc[4][4];
#pragma unroll
    for (int mf = 0; mf < 4; ++mf)
#pragma unroll
        for (int nf = 0; nf < 4; ++nf) acc[mf][nf] = {0.f, 0.f, 0.f, 0.f};

    uint2 rawA[4], rawB[4];
    bf16x8 af[8];

#define ISSUE_A(kk) {                                                        \
    _Pragma("unroll")                                                        \
    for (int i = 0; i < 4; ++i)                                              \
        __builtin_amdgcn_global_load_lds(                                    \
            (const AS1 void*)(agsrc[i] + (kk) * 64),                         \
            (AS3 void*)(Al + aoff[i]), 16, 0, 0); }

    ISSUE_A(0);
    load_raw(rawA, bsrc, 0);
    WAIT_V0_BAR;
    pack_b(rawA, Bl0, sb_);
    load_raw(rawB, bsrc, 1);
    read_af(af, Al, wm, l15, l4);
    WAIT_LG_BAR;
    ISSUE_A(1);

    do_mfma(acc, af, Bl0, wn, l15, l4);
    WAIT_V0_BAR;
    pack_b(rawB, Bl1, sb_);
    load_raw(rawA, bsrc, 2);
    read_af(af, Al, wm, l15, l4);
    WAIT_LG_BAR;
    ISSUE_A(2);

    do_mfma(acc, af, Bl1, wn, l15, l4);
    WAIT_V0_BAR;
    pack_b(rawA, Bl0, sb_);
    load_raw(rawB, bsrc, 3);
    read_af(af, Al, wm, l15, l4);
    WAIT_LG_BAR;
    ISSUE_A(3);

    do_mfma(acc, af, Bl0, wn, l15, l4);
    WAIT_V0_BAR;
    pack_b(rawB, Bl1, sb_);
    read_af(af, Al, wm, l15, l4);
    WAIT_LG_BAR;

    do_mfma(acc, af, Bl1, wn, l15, l4);
#undef ISSUE_A

    float* zb = z + (size_t)b * COUT * HW;
#pragma unroll
    for (int mf = 0; mf < 4; ++mf) {
        int obase = wm + mf * 16 + l4 * 4;
        float bb0 = b2[obase + 0], bb1 = b2[obase + 1];
        float bb2v = b2[obase + 2], bb3 = b2[obase + 3];
        float rmax[4] = {0.f, 0.f, 0.f, 0.f};
#pragma unroll
        for (int nf = 0; nf < 4; ++nf) {
            int n = n0 + wn + nf * 16 + l15;
            bool valid = (n < HW);
            float v0 = fmaxf(acc[mf][nf][0] + bb0, 0.f);
            float v1 = fmaxf(acc[mf][nf][1] + bb1, 0.f);
            float v2 = fmaxf(acc[mf][nf][2] + bb2v, 0.f);
            float v3 = fmaxf(acc[mf][nf][3] + bb3, 0.f);
            if (valid) {
                zb[(size_t)(obase + 0) * HW + n] = v0;
                zb[(size_t)(obase + 1) * HW + n] = v1;
                zb[(size_t)(obase + 2) * HW + n] = v2;
                zb[(size_t)(obase + 3) * HW + n] = v3;
                rmax[0] = fmaxf(rmax[0], v0);
                rmax[1] = fmaxf(rmax[1], v1);
                rmax[2] = fmaxf(rmax[2], v2);
                rmax[3] = fmaxf(rmax[3], v3);
            }
        }
#pragma unroll
        for (int r = 0; r < 4; ++r) {
            float v = rmax[r];
            v = fmaxf(v, __shfl_xor(v, 1, 64));
            v = fmaxf(v, __shfl_xor(v, 2, 64));
            v = fmaxf(v, __shfl_xor(v, 4, 64));
            v = fmaxf(v, __shfl_xor(v, 8, 64));
            if (l15 == 0)
                atomicMax(&pwmax[b * COUT + obase + r], __float_as_uint(v));
        }
    }
}

// ---------------- DIAGNOSTIC probes: slices of pw_kernel -------------------
// MODE bit0: B global loads + pack; bit1: MFMA; MODE==4: epilogue only.
// z written by MODE 4 is later fully overwritten by the real pw_kernel.
template<int MODE>
__global__ __launch_bounds__(512, 2) void pw_probe(
        const unsigned short* __restrict__ y, const unsigned short* __restrict__ Wp,
        const float* __restrict__ b2, float* __restrict__ z,
        unsigned* __restrict__ sinkmax, unsigned* __restrict__ sink) {
    constexpr bool DO_B = (MODE & 1) != 0;
    constexpr bool DO_M = (MODE & 2) != 0;

    __shared__ __align__(16) char lds[65536];
    char* Al  = lds;
    char* Bl0 = lds + 32768;
    char* Bl1 = lds + 49152;

    int bid0 = blockIdx.x;
    int bid = (bid0 & 7) * 100 + (bid0 >> 3);
    int b = bid / 25, nt = bid % 25;
    int n0 = nt * 128;

    int tid = threadIdx.x;
    int lane = tid & 63, wid = tid >> 6;
    int wm = (wid >> 1) * 64, wn = (wid & 1) * 64;
    int l15 = lane & 15, l4 = lane >> 4;

    f32x4 acc[4][4];
#pragma unroll
    for (int mf = 0; mf < 4; ++mf)
#pragma unroll
        for (int nf = 0; nf < 4; ++nf) acc[mf][nf] = {0.f, 0.f, 0.f, 0.f};

    unsigned lv = 1;

    if constexpr (MODE != 4) {
        const unsigned short* yb = y + (size_t)b * CIN * NPAD;
        const unsigned short* agsrc[4];
        int aoff[4];
#pragma unroll
        for (int i = 0; i < 4; ++i) {
            int s = i * 512 + tid;
            int m = s >> 3, cch = s & 7, dch = cch ^ (m & 7);
            agsrc[i] = Wp + m * 256 + dch * 8;
            aoff[i] = i * 8192 + wid * 1024;
        }
        int q = tid >> 5, nq = tid & 31;
        const unsigned short* bsrc = yb + q * 4 * NPAD + n0 + nq * 4;
        int sb_[4];
#pragma unroll
        for (int i2 = 0; i2 < 4; ++i2) {
            int nloc = nq * 4 + i2;
            sb_[i2] = nloc * 128 + (((q >> 1) ^ ((nloc >> 2) & 7)) << 4) + ((q & 1) << 3);
        }

        uint2 rawA[4], rawB[4];
        bf16x8 af[8];

#define ISSUE_AP(kk) {                                                       \
    _Pragma("unroll")                                                        \
    for (int i = 0; i < 4; ++i)                                              \
        __builtin_amdgcn_global_load_lds(                                    \
            (const AS1 void*)(agsrc[i] + (kk) * 64),                         \
            (AS3 void*)(Al + aoff[i]), 16, 0, 0); }

        ISSUE_AP(0);
        if constexpr (DO_B) load_raw(rawA, bsrc, 0);
        WAIT_V0_BAR;
        if constexpr (DO_B) { pack_b(rawA, Bl0, sb_); load_raw(rawB, bsrc, 1); }
        read_af(af, Al, wm, l15, l4);
        if constexpr (!DO_M) sink_af(af, lv);
        WAIT_LG_BAR;
        ISSUE_AP(1);

        if constexpr (DO_M) do_mfma(acc, af, Bl0, wn, l15, l4);
        else                sink_b(Bl0, wn, l15, l4, lv);
        WAIT_V0_BAR;
        if constexpr (DO_B) { pack_b(rawB, Bl1, sb_); load_raw(rawA, bsrc, 2); }
        read_af(af, Al, wm, l15, l4);
        if constexpr (!DO_M) sink_af(af, lv);
        WAIT_LG_BAR;
        ISSUE_AP(2);

        if constexpr (DO_M) do_mfma(acc, af, Bl1, wn, l15, l4);
        else                sink_b(Bl1, wn, l15, l4, lv);
        WAIT_V0_BAR;
        if constexpr (DO_B) { pack_b(rawA, Bl0, sb_); load_raw(rawB, bsrc, 3); }
        read_af(af, Al, wm, l15, l4);
        if constexpr (!DO_M) sink_af(af, lv);
        WAIT_LG_BAR;
        ISSUE_AP(3);

        if constexpr (DO_M) do_mfma(acc, af, Bl0, wn, l15, l4);
        else                sink_b(Bl0, wn, l15, l4, lv);
        WAIT_V0_BAR;
        if constexpr (DO_B) pack_b(rawB, Bl1, sb_);
        read_af(af, Al, wm, l15, l4);
        if constexpr (!DO_M) sink_af(af, lv);
        WAIT_LG_BAR;

        if constexpr (DO_M) do_mfma(acc, af, Bl1, wn, l15, l4);
        else                sink_b(Bl1, wn, l15, l4, lv);
#undef ISSUE_AP

        float fs = 0.f;
#pragma unroll
        for (int mf = 0; mf < 4; ++mf)
#pragma unroll
            for (int nf = 0; nf < 4; ++nf)
                fs += acc[mf][nf][0] + acc[mf][nf][1] + acc[mf][nf][2] + acc[mf][nf][3];
        lv ^= __float_as_uint(fs);
        asm volatile("" :: "v"(lv));
        if (lane == 0) sink[(blockIdx.x * 8 + wid) & 1023] = lv;
    } else {
        // epilogue only (acc = zeros); z overwritten later by real pw_kernel
        float* zb = z + (size_t)b * COUT * HW;
#pragma unroll
        for (int mf = 0; mf < 4; ++mf) {
            int obase = wm + mf * 16 + l4 * 4;
            float bb0 = b2[obase + 0], bb1 = b2[obase + 1];
            float bb2v = b2[obase + 2], bb3 = b2[obase + 3];
            float rmax[4] = {0.f, 0.f, 0.f, 0.f};
#pragma unroll
            for (int nf = 0; nf < 4; ++nf) {
                int n = n0 + wn + nf * 16 + l15;
                bool valid = (n < HW);
                float v0 = fmaxf(acc[mf][nf][0] + bb0, 0.f);
                float v1 = fmaxf(acc[mf][nf][1] + bb1, 0.f);
                float v2 = fmaxf(acc[mf][nf][2] + bb2v, 0.f);
                float v3 = fmaxf(acc[mf][nf][3] + bb3, 0.f);
                if (valid) {
                    zb[(size_t)(obase + 0) * HW + n] = v0;
                    zb[(size_t)(obase + 1) * HW + n] = v1;
                    zb[(size_t)(obase + 2) * HW + n] = v2;
                    zb[(size_t)(obase + 3) * HW + n] = v3;
                    rmax[0] = fmaxf(rmax[0], v0);
                    rmax[1] = fmaxf(rmax[1], v1);
                    rmax[2] = fmaxf(rmax[2], v2);
                    rmax[3] = fmaxf(rmax[3], v3);
                }
            }
#pragma unroll
            for (int r = 0; r < 4; ++r) {
                float v = rmax[r];
                v = fmaxf(v, __shfl_xor(v, 1, 64));
                v = fmaxf(v, __shfl_xor(v, 2, 64));
                v = fmaxf(v, __shfl_xor(v, 4, 64));
                v = fmaxf(v, __shfl_xor(v, 8, 64));
                if (l15 == 0)
                    atomicMax(&sinkmax[b * COUT + obase + r], __float_as_uint(v));
            }
        }
    }
}

// ---------------- K3: apply pointwise cut ---------------------------------
__global__ __launch_bounds__(256) void cut_kernel(const unsigned* __restrict__ pwmax,
                                                  float* __restrict__ z) {
    int base = blockIdx.x * 8;
#pragma unroll
    for (int j = 0; j < 8; ++j) {
        int bo = base + j;
        if (__uint_as_float(pwmax[bo]) >= 1e-3f) continue;
        float4* zp = (float4*)(z + (size_t)bo * HW);
        for (int i = threadIdx.x; i < HW / 4; i += 256)
            zp[i] = make_float4(0.f, 0.f, 0.f, 0.f);
    }
}

extern "C" void kernel_launch(void* const* d_in, const int* in_sizes, int n_in,
                              void* d_out, int out_size, void* d_ws, size_t ws_size,
                              hipStream_t stream) {
    const float* x   = (const float*)d_in[0];
    const float* dww = (const float*)d_in[1];
    const float* dwb = (const float*)d_in[2];
    const float* g1  = (const float*)d_in[3];
    const float* be1 = (const float*)d_in[4];
    const float* mu1 = (const float*)d_in[5];
    const float* va1 = (const float*)d_in[6];
    const float* pww = (const float*)d_in[7];
    const float* pwb = (const float*)d_in[8];
    const float* g2  = (const float*)d_in[9];
    const float* be2 = (const float*)d_in[10];
    const float* mu2 = (const float*)d_in[11];
    const float* va2 = (const float*)d_in[12];
    float* z = (float*)d_out;

    char* ws = (char*)d_ws;
    const size_t Y_BYTES = (size_t)BATCH * CIN * NPAD * 2;  // 52,428,800
    unsigned short* y  = (unsigned short*)ws;
    unsigned short* Wp = (unsigned short*)(ws + Y_BYTES);
    float* b2          = (float*)(ws + Y_BYTES + 131072);
    unsigned* pwmax    = (unsigned*)(ws + Y_BYTES + 131072 + 1024);
    unsigned* sinkmax  = (unsigned*)(ws + Y_BYTES + 131072 + 1024 + 32768);
    unsigned* sink     = (unsigned*)(ws + Y_BYTES + 131072 + 1024 + 65536);

    prep_kernel<<<256, 256, 0, stream>>>(pww, pwb, g2, be2, mu2, va2, Wp, b2, pwmax);
    dw_kernel<<<2048, 256, 0, stream>>>(x, dww, dwb, g1, be1, mu1, va1, y);

    // diagnostic slices of pw (see decision table in commit message)
    pw_probe<0><<<800, 512, 0, stream>>>(y, Wp, b2, z, sinkmax, sink);  // skeleton
    pw_probe<2><<<800, 512, 0, stream>>>(y, Wp, b2, z, sinkmax, sink);  // A+MFMA
    pw_probe<1><<<800, 512, 0, stream>>>(y, Wp, b2, z, sinkmax, sink);  // mem path
    pw_probe<3><<<800, 512, 0, stream>>>(y, Wp, b2, z, sinkmax, sink);  // all but epi
    pw_probe<4><<<800, 512, 0, stream>>>(y, Wp, b2, z, sinkmax, sink);  // epi only

    pw_kernel<<<800, 512, 0, stream>>>(y, Wp, b2, z, pwmax);
    cut_kernel<<<BATCH * COUT / 8, 256, 0, stream>>>(pwmax, z);
}

// Round 11
// 103.704 us; speedup vs baseline: 1.9837x; 1.9837x over previous
//
#include <hip/hip_runtime.h>
#include <hip/hip_bf16.h>
#include <stdint.h>

#define BATCH 32
#define CIN   256
#define COUT  256
#define HW    3136   // 56*56
#define NPAD  3200   // pad HW to multiple of 128

#define AS1 __attribute__((address_space(1)))
#define AS3 __attribute__((address_space(3)))

typedef short bf16x8 __attribute__((ext_vector_type(8)));
typedef float f32x4  __attribute__((ext_vector_type(4)));

__device__ __forceinline__ unsigned short f2bf(float f) {
    unsigned u = __float_as_uint(f);
    u += 0x7fffu + ((u >> 16) & 1u);   // round-to-nearest-even
    return (unsigned short)(u >> 16);
}

// ---------------- K0: fold BN2 into pw weights; zero pwmax -----------------
__global__ __launch_bounds__(256) void prep_kernel(
        const float* __restrict__ pw_w, const float* __restrict__ pw_b,
        const float* __restrict__ g2, const float* __restrict__ be2,
        const float* __restrict__ mu2, const float* __restrict__ va2,
        unsigned short* __restrict__ Wp, float* __restrict__ b2,
        unsigned* __restrict__ pwmax) {
    int o = blockIdx.x;
    int t = threadIdx.x;
    float inv2 = g2[o] * rsqrtf(va2[o] + 1e-5f);
    Wp[o * CIN + t] = f2bf(pw_w[o * CIN + t] * inv2);
    if (t == 0) b2[o] = pw_b[o] * inv2 + be2[o] - mu2[o] * inv2;
    int idx = blockIdx.x * 256 + t;
    if (idx < BATCH * COUT) pwmax[idx] = 0u;
}

// ---------------- K1: depthwise 3x3 + BN1 + ReLU + SELF-CUT -> y bf16 -----
__global__ __launch_bounds__(256) void dw_kernel(
        const float* __restrict__ x, const float* __restrict__ dww,
        const float* __restrict__ dwb,
        const float* __restrict__ g1, const float* __restrict__ be1,
        const float* __restrict__ mu1, const float* __restrict__ va1,
        unsigned short* __restrict__ y) {
    __shared__ float xs[4 * 3136];
    int tid  = threadIdx.x;
    int lane = tid & 63, wid = tid >> 6;
    int plane = blockIdx.x * 4 + wid;
    int c = plane & 255;

    const float* xp = x + (size_t)plane * HW;
    float* xw = xs + wid * 3136;

#pragma unroll
    for (int i = 0; i < 12; ++i)
        __builtin_amdgcn_global_load_lds(
            (const AS1 void*)(xp + i * 256 + lane * 4),
            (AS3 void*)(xw + i * 256), 16, 0, 0);
    __builtin_amdgcn_global_load_lds(
        (const AS1 void*)(xp + 3072 + lane),
        (AS3 void*)(xw + 3072), 4, 0, 0);

    float w00 = dww[c*9+0], w01 = dww[c*9+1], w02 = dww[c*9+2];
    float w10 = dww[c*9+3], w11 = dww[c*9+4], w12 = dww[c*9+5];
    float w20 = dww[c*9+6], w21 = dww[c*9+7], w22 = dww[c*9+8];
    float inv = g1[c] * rsqrtf(va1[c] + 1e-5f);
    float b0  = dwb[c] * inv + (be1[c] - mu1[c] * inv);

    int  col    = lane < 56 ? lane : 55;
    bool active = lane < 56;
    if (lane == 0)  { w00 = 0.f; w10 = 0.f; w20 = 0.f; }
    if (lane >= 55) { w02 = 0.f; w12 = 0.f; w22 = 0.f; }
    int il = (lane == 0) ? 0 : col - 1;
    int ir = (col == 55) ? 55 : col + 1;

    asm volatile("s_waitcnt vmcnt(0)" ::: "memory");
    __builtin_amdgcn_sched_barrier(0);

    const float* xb = xw;
    unsigned short* yp = y + (size_t)plane * NPAD + col;

    float A = 0.f;
    float Bv = 0.f;
    float lmax = 0.f;
#pragma unroll
    for (int q = 0; q < 56; q += 2) {
        float l0 = xb[q*56 + il],      c0 = xb[q*56 + col],      r0 = xb[q*56 + ir];
        float l1 = xb[(q+1)*56 + il],  c1 = xb[(q+1)*56 + col],  r1 = xb[(q+1)*56 + ir];
        if (q > 0) {
            float o0 = fmaf(l0, w20, fmaf(c0, w21, fmaf(r0, w22, A)));
            float v = fmaxf(fmaf(o0, inv, b0), 0.f);
            if (active) { lmax = fmaxf(lmax, v); yp[(q-1)*56] = f2bf(v); }
        }
        {
            float o1 = fmaf(l0, w10, fmaf(c0, w11, fmaf(r0, w12,
                       fmaf(l1, w20, fmaf(c1, w21, fmaf(r1, w22, Bv))))));
            float v = fmaxf(fmaf(o1, inv, b0), 0.f);
            if (active) { lmax = fmaxf(lmax, v); yp[q*56] = f2bf(v); }
        }
        float top0 = fmaf(l0, w00, fmaf(c0, w01, r0 * w02));
        A  = fmaf(l1, w10, fmaf(c1, w11, fmaf(r1, w12, top0)));
        Bv = fmaf(l1, w00, fmaf(c1, w01, r1 * w02));
    }
    {
        float v = fmaxf(fmaf(A, inv, b0), 0.f);
        if (active) { lmax = fmaxf(lmax, v); yp[55*56] = f2bf(v); }
    }
    for (int off = 32; off >= 1; off >>= 1)
        lmax = fmaxf(lmax, __shfl_xor(lmax, off, 64));
    if (lane < 8) *(uint4*)(y + (size_t)plane * NPAD + HW + lane * 8)
        = make_uint4(0, 0, 0, 0);
    if (lmax < 4.0f) {
        asm volatile("s_waitcnt vmcnt(0)" ::: "memory");
        unsigned short* yp0 = y + (size_t)plane * NPAD;
#pragma unroll
        for (int it = 0; it < 7; ++it) {
            int idx = it * 64 + lane;
            if (idx < 392) *(uint4*)(yp0 + idx * 8) = make_uint4(0, 0, 0, 0);
        }
    }
}

// ---------------- K2 helpers ----------------------------------------------
__device__ __forceinline__ void load_raw(uint2* dst, const unsigned short* bsrc, int kk) {
#pragma unroll
    for (int r = 0; r < 4; ++r)
        dst[r] = *(const uint2*)(bsrc + (size_t)(kk * 64 + r) * NPAD);
}

__device__ __forceinline__ void pack_b(const uint2* src, char* dstbase,
                                       const int* sb_) {
    uint2 r0 = src[0], r1 = src[1], r2 = src[2], r3 = src[3];
#pragma unroll
    for (int i2 = 0; i2 < 4; ++i2) {
        unsigned x0 = (i2 & 2) ? r0.y : r0.x;
        unsigned x1 = (i2 & 2) ? r1.y : r1.x;
        unsigned x2 = (i2 & 2) ? r2.y : r2.x;
        unsigned x3 = (i2 & 2) ? r3.y : r3.x;
        if (i2 & 1) { x0 >>= 16; x2 >>= 16; }
        else        { x0 &= 0xffffu; x2 &= 0xffffu; }
        unsigned px = (i2 & 1) ? (x0 | (x1 & 0xffff0000u)) : (x0 | (x1 << 16));
        unsigned py = (i2 & 1) ? (x2 | (x3 & 0xffff0000u)) : (x2 | (x3 << 16));
        *(uint2*)(dstbase + sb_[i2]) = make_uint2(px, py);
    }
}

__device__ __forceinline__ void read_af(bf16x8* af, const char* Al,
                                        int wm, int l15, int l4) {
#pragma unroll
    for (int h = 0; h < 2; ++h)
#pragma unroll
        for (int mf = 0; mf < 4; ++mf) {
            int m = wm + mf * 16 + l15;
            int cc = h * 4 + l4;
            af[h * 4 + mf] = *(const bf16x8*)(Al + m * 128 + ((cc ^ (m & 7)) << 4));
        }
}

__device__ __forceinline__ void do_mfma(f32x4 (*acc)[4], const bf16x8* af,
                                        const char* Blb, int wn, int l15, int l4) {
#pragma unroll
    for (int h = 0; h < 2; ++h) {
        bf16x8 bfr[4];
        int cc = h * 4 + l4;
#pragma unroll
        for (int nf = 0; nf < 4; ++nf) {
            int n = wn + nf * 16 + l15;
            bfr[nf] = *(const bf16x8*)(Blb + n * 128 + ((cc ^ ((n >> 2) & 7)) << 4));
        }
#pragma unroll
        for (int mf = 0; mf < 4; ++mf)
#pragma unroll
            for (int nf = 0; nf < 4; ++nf)
                acc[mf][nf] = __builtin_amdgcn_mfma_f32_16x16x32_bf16(
                    af[h * 4 + mf], bfr[nf], acc[mf][nf], 0, 0, 0);
    }
}

#define WAIT_V0_BAR  { asm volatile("s_waitcnt vmcnt(0)" ::: "memory");   \
                       __builtin_amdgcn_sched_barrier(0);                  \
                       __builtin_amdgcn_s_barrier();                       \
                       __builtin_amdgcn_sched_barrier(0); }
#define WAIT_LG_BAR  { asm volatile("s_waitcnt lgkmcnt(0)" ::: "memory"); \
                       __builtin_amdgcn_sched_barrier(0);                  \
                       __builtin_amdgcn_s_barrier();                       \
                       __builtin_amdgcn_sched_barrier(0); }

// ---------------- K2: pointwise GEMM + BN2 + ReLU, coalesced epilogue ------
// K-loop identical to R8 (verified). Epilogue v2: acc -> LDS transpose in
// 2 passes of 128 o-rows (64KB), then contiguous 512B-per-instruction
// float2 stores to z. rmax/atomics computed from acc regs as before.
__global__ __launch_bounds__(512, 2) void pw_kernel(
        const unsigned short* __restrict__ y, const unsigned short* __restrict__ Wp,
        const float* __restrict__ b2, float* __restrict__ z,
        unsigned* __restrict__ pwmax) {
    __shared__ __align__(16) char lds[65536];
    char* Al  = lds;
    char* Bl0 = lds + 32768;
    char* Bl1 = lds + 49152;

    int bid0 = blockIdx.x;                      // 800
    int bid = (bid0 & 7) * 100 + (bid0 >> 3);
    int b = bid / 25, nt = bid % 25;
    int n0 = nt * 128;

    int tid = threadIdx.x;
    int lane = tid & 63, wid = tid >> 6;
    int wm = (wid >> 1) * 64, wn = (wid & 1) * 64;
    int l15 = lane & 15, l4 = lane >> 4;

    const unsigned short* yb = y + (size_t)b * CIN * NPAD;

    const unsigned short* agsrc[4];
    int aoff[4];
#pragma unroll
    for (int i = 0; i < 4; ++i) {
        int s = i * 512 + tid;
        int m = s >> 3, cch = s & 7, dch = cch ^ (m & 7);
        agsrc[i] = Wp + m * 256 + dch * 8;
        aoff[i] = i * 8192 + wid * 1024;
    }
    int q = tid >> 5, nq = tid & 31;
    const unsigned short* bsrc = yb + q * 4 * NPAD + n0 + nq * 4;
    int sb_[4];
#pragma unroll
    for (int i2 = 0; i2 < 4; ++i2) {
        int nloc = nq * 4 + i2;
        sb_[i2] = nloc * 128 + (((q >> 1) ^ ((nloc >> 2) & 7)) << 4) + ((q & 1) << 3);
    }

    f32x4 acc[4][4];
#pragma unroll
    for (int mf = 0; mf < 4; ++mf)
#pragma unroll
        for (int nf = 0; nf < 4; ++nf) acc[mf][nf] = {0.f, 0.f, 0.f, 0.f};

    uint2 rawA[4], rawB[4];
    bf16x8 af[8];

#define ISSUE_A(kk) {                                                        \
    _Pragma("unroll")                                                        \
    for (int i = 0; i < 4; ++i)                                              \
        __builtin_amdgcn_global_load_lds(                                    \
            (const AS1 void*)(agsrc[i] + (kk) * 64),                         \
            (AS3 void*)(Al + aoff[i]), 16, 0, 0); }

    ISSUE_A(0);
    load_raw(rawA, bsrc, 0);
    WAIT_V0_BAR;
    pack_b(rawA, Bl0, sb_);
    load_raw(rawB, bsrc, 1);
    read_af(af, Al, wm, l15, l4);
    WAIT_LG_BAR;
    ISSUE_A(1);

    do_mfma(acc, af, Bl0, wn, l15, l4);
    WAIT_V0_BAR;
    pack_b(rawB, Bl1, sb_);
    load_raw(rawA, bsrc, 2);
    read_af(af, Al, wm, l15, l4);
    WAIT_LG_BAR;
    ISSUE_A(2);

    do_mfma(acc, af, Bl1, wn, l15, l4);
    WAIT_V0_BAR;
    pack_b(rawA, Bl0, sb_);
    load_raw(rawB, bsrc, 3);
    read_af(af, Al, wm, l15, l4);
    WAIT_LG_BAR;
    ISSUE_A(3);

    do_mfma(acc, af, Bl0, wn, l15, l4);
    WAIT_V0_BAR;
    pack_b(rawB, Bl1, sb_);
    read_af(af, Al, wm, l15, l4);
    WAIT_LG_BAR;

    do_mfma(acc, af, Bl1, wn, l15, l4);
#undef ISSUE_A

    // ---- bias + relu into acc; rmax + atomics from regs ----
#pragma unroll
    for (int mf = 0; mf < 4; ++mf) {
        int obase = wm + mf * 16 + l4 * 4;
        float bb0 = b2[obase + 0], bb1 = b2[obase + 1];
        float bb2v = b2[obase + 2], bb3 = b2[obase + 3];
        float rmax[4] = {0.f, 0.f, 0.f, 0.f};
#pragma unroll
        for (int nf = 0; nf < 4; ++nf) {
            int n = n0 + wn + nf * 16 + l15;
            bool valid = (n < HW);
            float v0 = fmaxf(acc[mf][nf][0] + bb0, 0.f);
            float v1 = fmaxf(acc[mf][nf][1] + bb1, 0.f);
            float v2 = fmaxf(acc[mf][nf][2] + bb2v, 0.f);
            float v3 = fmaxf(acc[mf][nf][3] + bb3, 0.f);
            acc[mf][nf][0] = v0; acc[mf][nf][1] = v1;
            acc[mf][nf][2] = v2; acc[mf][nf][3] = v3;
            if (valid) {
                rmax[0] = fmaxf(rmax[0], v0);
                rmax[1] = fmaxf(rmax[1], v1);
                rmax[2] = fmaxf(rmax[2], v2);
                rmax[3] = fmaxf(rmax[3], v3);
            }
        }
#pragma unroll
        for (int r = 0; r < 4; ++r) {
            float v = rmax[r];
            v = fmaxf(v, __shfl_xor(v, 1, 64));
            v = fmaxf(v, __shfl_xor(v, 2, 64));
            v = fmaxf(v, __shfl_xor(v, 4, 64));
            v = fmaxf(v, __shfl_xor(v, 8, 64));
            if (l15 == 0)
                atomicMax(&pwmax[b * COUT + obase + r], __float_as_uint(v));
        }
    }

    // ---- LDS-transpose coalesced z store: 2 passes x 128 o-rows ----
    float* zb = z + (size_t)b * COUT * HW;
    float* T = (float*)lds;                  // 128 x 128 fp32 = 64KB
    int nvalid = HW - n0;                    // 128, or 64 for nt==24
    __builtin_amdgcn_s_barrier();            // all LDS (Bl1/Al) reads done
#pragma unroll
    for (int pass = 0; pass < 2; ++pass) {
        if ((wid >> 2) == pass) {
            int ob = wm - pass * 128;        // 0 or 64 within pass
#pragma unroll
            for (int mf = 0; mf < 4; ++mf)
#pragma unroll
                for (int nf = 0; nf < 4; ++nf) {
                    int nl = wn + nf * 16 + l15;
                    int ol = ob + mf * 16 + l4 * 4;
#pragma unroll
                    for (int j = 0; j < 4; ++j)
                        T[(ol + j) * 128 + nl] = acc[mf][nf][j];
                }
        }
        __builtin_amdgcn_s_barrier();
        // all 8 waves: each stores 16 rows, 512B contiguous per instruction
#pragma unroll
        for (int rr = 0; rr < 16; ++rr) {
            int ol = wid * 16 + rr;
            int o  = pass * 128 + ol;
            if (2 * lane < nvalid) {
                float2 v = *(float2*)&T[ol * 128 + lane * 2];
                *(float2*)&zb[(size_t)o * HW + n0 + lane * 2] = v;
            }
        }
        __builtin_amdgcn_s_barrier();
    }
}

// ---------------- K3: apply pointwise cut ---------------------------------
__global__ __launch_bounds__(256) void cut_kernel(const unsigned* __restrict__ pwmax,
                                                  float* __restrict__ z) {
    int base = blockIdx.x * 8;
#pragma unroll
    for (int j = 0; j < 8; ++j) {
        int bo = base + j;
        if (__uint_as_float(pwmax[bo]) >= 1e-3f) continue;
        float4* zp = (float4*)(z + (size_t)bo * HW);
        for (int i = threadIdx.x; i < HW / 4; i += 256)
            zp[i] = make_float4(0.f, 0.f, 0.f, 0.f);
    }
}

extern "C" void kernel_launch(void* const* d_in, const int* in_sizes, int n_in,
                              void* d_out, int out_size, void* d_ws, size_t ws_size,
                              hipStream_t stream) {
    const float* x   = (const float*)d_in[0];
    const float* dww = (const float*)d_in[1];
    const float* dwb = (const float*)d_in[2];
    const float* g1  = (const float*)d_in[3];
    const float* be1 = (const float*)d_in[4];
    const float* mu1 = (const float*)d_in[5];
    const float* va1 = (const float*)d_in[6];
    const float* pww = (const float*)d_in[7];
    const float* pwb = (const float*)d_in[8];
    const float* g2  = (const float*)d_in[9];
    const float* be2 = (const float*)d_in[10];
    const float* mu2 = (const float*)d_in[11];
    const float* va2 = (const float*)d_in[12];
    float* z = (float*)d_out;

    char* ws = (char*)d_ws;
    const size_t Y_BYTES = (size_t)BATCH * CIN * NPAD * 2;  // 52,428,800
    unsigned short* y  = (unsigned short*)ws;
    unsigned short* Wp = (unsigned short*)(ws + Y_BYTES);
    float* b2          = (float*)(ws + Y_BYTES + 131072);
    unsigned* pwmax    = (unsigned*)(ws + Y_BYTES + 131072 + 1024);

    prep_kernel<<<256, 256, 0, stream>>>(pww, pwb, g2, be2, mu2, va2, Wp, b2, pwmax);
    dw_kernel<<<2048, 256, 0, stream>>>(x, dww, dwb, g1, be1, mu1, va1, y);
    pw_kernel<<<800, 512, 0, stream>>>(y, Wp, b2, z, pwmax);
    cut_kernel<<<BATCH * COUT / 8, 256, 0, stream>>>(pwmax, z);
}

// Round 12
// 100.446 us; speedup vs baseline: 2.0480x; 1.0324x over previous
//
#include <hip/hip_runtime.h>
#include <hip/hip_bf16.h>
#include <stdint.h>

#define BATCH 32
#define CIN   256
#define COUT  256
#define HW    3136   // 56*56
#define NPAD  3200   // pad HW to multiple of 128

#define AS1 __attribute__((address_space(1)))
#define AS3 __attribute__((address_space(3)))

typedef short bf16x8 __attribute__((ext_vector_type(8)));
typedef float f32x4  __attribute__((ext_vector_type(4)));

__device__ __forceinline__ unsigned short f2bf(float f) {
    unsigned u = __float_as_uint(f);
    u += 0x7fffu + ((u >> 16) & 1u);   // round-to-nearest-even
    return (unsigned short)(u >> 16);
}

// ---------------- K0: fold BN2 into pw weights; zero pwmax -----------------
__global__ __launch_bounds__(256) void prep_kernel(
        const float* __restrict__ pw_w, const float* __restrict__ pw_b,
        const float* __restrict__ g2, const float* __restrict__ be2,
        const float* __restrict__ mu2, const float* __restrict__ va2,
        unsigned short* __restrict__ Wp, float* __restrict__ b2,
        unsigned* __restrict__ pwmax) {
    int o = blockIdx.x;
    int t = threadIdx.x;
    float inv2 = g2[o] * rsqrtf(va2[o] + 1e-5f);
    Wp[o * CIN + t] = f2bf(pw_w[o * CIN + t] * inv2);
    if (t == 0) b2[o] = pw_b[o] * inv2 + be2[o] - mu2[o] * inv2;
    int idx = blockIdx.x * 256 + t;
    if (idx < BATCH * COUT) pwmax[idx] = 0u;
}

// ---------------- K1: depthwise 3x3 + BN1 + ReLU + SELF-CUT -> y bf16 -----
__global__ __launch_bounds__(256) void dw_kernel(
        const float* __restrict__ x, const float* __restrict__ dww,
        const float* __restrict__ dwb,
        const float* __restrict__ g1, const float* __restrict__ be1,
        const float* __restrict__ mu1, const float* __restrict__ va1,
        unsigned short* __restrict__ y) {
    __shared__ float xs[4 * 3136];
    int tid  = threadIdx.x;
    int lane = tid & 63, wid = tid >> 6;
    int plane = blockIdx.x * 4 + wid;
    int c = plane & 255;

    const float* xp = x + (size_t)plane * HW;
    float* xw = xs + wid * 3136;

#pragma unroll
    for (int i = 0; i < 12; ++i)
        __builtin_amdgcn_global_load_lds(
            (const AS1 void*)(xp + i * 256 + lane * 4),
            (AS3 void*)(xw + i * 256), 16, 0, 0);
    __builtin_amdgcn_global_load_lds(
        (const AS1 void*)(xp + 3072 + lane),
        (AS3 void*)(xw + 3072), 4, 0, 0);

    float w00 = dww[c*9+0], w01 = dww[c*9+1], w02 = dww[c*9+2];
    float w10 = dww[c*9+3], w11 = dww[c*9+4], w12 = dww[c*9+5];
    float w20 = dww[c*9+6], w21 = dww[c*9+7], w22 = dww[c*9+8];
    float inv = g1[c] * rsqrtf(va1[c] + 1e-5f);
    float b0  = dwb[c] * inv + (be1[c] - mu1[c] * inv);

    int  col    = lane < 56 ? lane : 55;
    bool active = lane < 56;
    if (lane == 0)  { w00 = 0.f; w10 = 0.f; w20 = 0.f; }
    if (lane >= 55) { w02 = 0.f; w12 = 0.f; w22 = 0.f; }
    int il = (lane == 0) ? 0 : col - 1;
    int ir = (col == 55) ? 55 : col + 1;

    asm volatile("s_waitcnt vmcnt(0)" ::: "memory");
    __builtin_amdgcn_sched_barrier(0);

    const float* xb = xw;
    unsigned short* yp = y + (size_t)plane * NPAD + col;

    float A = 0.f;
    float Bv = 0.f;
    float lmax = 0.f;
#pragma unroll
    for (int q = 0; q < 56; q += 2) {
        float l0 = xb[q*56 + il],      c0 = xb[q*56 + col],      r0 = xb[q*56 + ir];
        float l1 = xb[(q+1)*56 + il],  c1 = xb[(q+1)*56 + col],  r1 = xb[(q+1)*56 + ir];
        if (q > 0) {
            float o0 = fmaf(l0, w20, fmaf(c0, w21, fmaf(r0, w22, A)));
            float v = fmaxf(fmaf(o0, inv, b0), 0.f);
            if (active) { lmax = fmaxf(lmax, v); yp[(q-1)*56] = f2bf(v); }
        }
        {
            float o1 = fmaf(l0, w10, fmaf(c0, w11, fmaf(r0, w12,
                       fmaf(l1, w20, fmaf(c1, w21, fmaf(r1, w22, Bv))))));
            float v = fmaxf(fmaf(o1, inv, b0), 0.f);
            if (active) { lmax = fmaxf(lmax, v); yp[q*56] = f2bf(v); }
        }
        float top0 = fmaf(l0, w00, fmaf(c0, w01, r0 * w02));
        A  = fmaf(l1, w10, fmaf(c1, w11, fmaf(r1, w12, top0)));
        Bv = fmaf(l1, w00, fmaf(c1, w01, r1 * w02));
    }
    {
        float v = fmaxf(fmaf(A, inv, b0), 0.f);
        if (active) { lmax = fmaxf(lmax, v); yp[55*56] = f2bf(v); }
    }
    for (int off = 32; off >= 1; off >>= 1)
        lmax = fmaxf(lmax, __shfl_xor(lmax, off, 64));
    if (lane < 8) *(uint4*)(y + (size_t)plane * NPAD + HW + lane * 8)
        = make_uint4(0, 0, 0, 0);
    if (lmax < 4.0f) {
        asm volatile("s_waitcnt vmcnt(0)" ::: "memory");
        unsigned short* yp0 = y + (size_t)plane * NPAD;
#pragma unroll
        for (int it = 0; it < 7; ++it) {
            int idx = it * 64 + lane;
            if (idx < 392) *(uint4*)(yp0 + idx * 8) = make_uint4(0, 0, 0, 0);
        }
    }
}

// ---------------- K2 helpers ----------------------------------------------
__device__ __forceinline__ void pack_b(const uint2* src, char* dstbase,
                                       const int* sb_) {
    uint2 r0 = src[0], r1 = src[1], r2 = src[2], r3 = src[3];
#pragma unroll
    for (int i2 = 0; i2 < 4; ++i2) {
        unsigned x0 = (i2 & 2) ? r0.y : r0.x;
        unsigned x1 = (i2 & 2) ? r1.y : r1.x;
        unsigned x2 = (i2 & 2) ? r2.y : r2.x;
        unsigned x3 = (i2 & 2) ? r3.y : r3.x;
        if (i2 & 1) { x0 >>= 16; x2 >>= 16; }
        else        { x0 &= 0xffffu; x2 &= 0xffffu; }
        unsigned px = (i2 & 1) ? (x0 | (x1 & 0xffff0000u)) : (x0 | (x1 << 16));
        unsigned py = (i2 & 1) ? (x2 | (x3 & 0xffff0000u)) : (x2 | (x3 << 16));
        *(uint2*)(dstbase + sb_[i2]) = make_uint2(px, py);
    }
}

// ---------------- K2: b-amortized pointwise GEMM ---------------------------
// Tile 64o x 128n, 4 waves (wave 32x64), TWO batches per block (8 K-steps).
// A (64x256, 32KB LDS) staged ONCE via pre-swizzled global_load_lds.
// B double-buffered 16KB; praw reg double-buffer -> counted vmcnt(8)
// (next step's loads in flight before each wait; drain only at last step).
__global__ __launch_bounds__(256, 2) void pw_kernel(
        const unsigned short* __restrict__ y, const unsigned short* __restrict__ Wp,
        const float* __restrict__ b2, float* __restrict__ z,
        unsigned* __restrict__ pwmax) {
    __shared__ __align__(16) char lds[65536];
    char* Al  = lds;            // 32KB [m:64][cc:32 chunks swizzled by m&7]
    char* Bl0 = lds + 32768;    // 16KB
    char* Bl1 = lds + 49152;    // 16KB

    int bid0 = blockIdx.x;                      // 1600 = 8 * 200
    int bid  = (bid0 & 7) * 200 + (bid0 >> 3);  // XCD swizzle (bijective)
    int ot   = bid & 3;
    int rest = bid >> 2;
    int nt   = rest % 25;
    int bg   = rest / 25;                       // 0..15
    int o0 = ot * 64, n0 = nt * 128;
    int b0 = bg * 2, b1 = b0 + 1;

    int tid = threadIdx.x;
    int lane = tid & 63, wid = tid >> 6;
    int wm = (wid >> 1) * 32, wn = (wid & 1) * 64;
    int l15 = lane & 15, l4 = lane >> 4;

    const unsigned short* yb0 = y + (size_t)b0 * CIN * NPAD;
    const unsigned short* yb1 = y + (size_t)b1 * CIN * NPAD;

    // ---- A staging: 8 DMA issues, linear dest byte = slot*16 ----
#pragma unroll
    for (int i = 0; i < 8; ++i) {
        int s = i * 256 + tid;
        int m = s >> 5, cch = s & 31, dch = cch ^ (m & 7);
        __builtin_amdgcn_global_load_lds(
            (const AS1 void*)(Wp + (size_t)(o0 + m) * CIN + dch * 8),
            (AS3 void*)(Al + i * 4096 + wid * 1024), 16, 0, 0);
    }

    // ---- B geometry: thread owns 8 k-rows x 4 n ----
    int q = tid >> 5, nq = tid & 31;            // q: 8-row group, nq: n-quad
    size_t boff = (size_t)(q * 8) * NPAD + n0 + nq * 4;
    int sbA[4], sbB[4];
#pragma unroll
    for (int i2 = 0; i2 < 4; ++i2) {
        int nloc = nq * 4 + i2;
        sbA[i2] = nloc * 128 + ((q ^ ((nloc >> 2) & 7)) << 4);
        sbB[i2] = sbA[i2] + 8;
    }

    uint2 praw0[8], praw1[8];
#define LOADB(dst, ybp, kk) { _Pragma("unroll")                              \
    for (int r = 0; r < 8; ++r)                                              \
        dst[r] = *(const uint2*)((ybp) + boff + (size_t)((kk) * 64 + r) * NPAD); }
#define PACKB(src, Blb) { pack_b(src, Blb, sbA); pack_b(src + 4, Blb, sbB); }
#define VM8   { asm volatile("s_waitcnt vmcnt(8)" ::: "memory"); __builtin_amdgcn_sched_barrier(0); }
#define VM0   { asm volatile("s_waitcnt vmcnt(0)" ::: "memory"); __builtin_amdgcn_sched_barrier(0); }
#define LGBAR { asm volatile("s_waitcnt lgkmcnt(0)" ::: "memory");           \
                __builtin_amdgcn_sched_barrier(0);                           \
                __builtin_amdgcn_s_barrier();                                \
                __builtin_amdgcn_sched_barrier(0); }

    f32x4 accA[2][4], accB[2][4];
#pragma unroll
    for (int mf = 0; mf < 2; ++mf)
#pragma unroll
        for (int nf = 0; nf < 4; ++nf) {
            accA[mf][nf] = {0.f, 0.f, 0.f, 0.f};
            accB[mf][nf] = {0.f, 0.f, 0.f, 0.f};
        }

#define STEPM(ACC, KK, BLB) { _Pragma("unroll") for (int h = 0; h < 2; ++h) { \
        bf16x8 afr[2], bfr[4];                                                \
        int cc = (KK) * 8 + h * 4 + l4;                                       \
        _Pragma("unroll") for (int mf = 0; mf < 2; ++mf) {                    \
            int m = wm + mf * 16 + l15;                                       \
            afr[mf] = *(const bf16x8*)(Al + m * 512 + ((cc ^ (m & 7)) << 4)); } \
        int cb = h * 4 + l4;                                                  \
        _Pragma("unroll") for (int nf = 0; nf < 4; ++nf) {                    \
            int n = wn + nf * 16 + l15;                                       \
            bfr[nf] = *(const bf16x8*)((BLB) + n * 128 + ((cb ^ ((n >> 2) & 7)) << 4)); } \
        _Pragma("unroll") for (int mf = 0; mf < 2; ++mf)                      \
            _Pragma("unroll") for (int nf = 0; nf < 4; ++nf)                  \
                ACC[mf][nf] = __builtin_amdgcn_mfma_f32_16x16x32_bf16(        \
                    afr[mf], bfr[nf], ACC[mf][nf], 0, 0, 0); } }

    // ---- prologue ----
    LOADB(praw0, yb0, 0);
    VM8;                                   // A DMA (8 oldest) done
    __builtin_amdgcn_s_barrier();          // A visible to all waves
    __builtin_amdgcn_sched_barrier(0);

    // 8 steps, counted vmcnt, one barrier per step
    LOADB(praw1, yb0, 1); VM8; PACKB(praw0, Bl0); LGBAR; STEPM(accA, 0, Bl0);
    LOADB(praw0, yb0, 2); VM8; PACKB(praw1, Bl1); LGBAR; STEPM(accA, 1, Bl1);
    LOADB(praw1, yb0, 3); VM8; PACKB(praw0, Bl0); LGBAR; STEPM(accA, 2, Bl0);
    LOADB(praw0, yb1, 0); VM8; PACKB(praw1, Bl1); LGBAR; STEPM(accA, 3, Bl1);
    LOADB(praw1, yb1, 1); VM8; PACKB(praw0, Bl0); LGBAR; STEPM(accB, 0, Bl0);
    LOADB(praw0, yb1, 2); VM8; PACKB(praw1, Bl1); LGBAR; STEPM(accB, 1, Bl1);
    LOADB(praw1, yb1, 3); VM8; PACKB(praw0, Bl0); LGBAR; STEPM(accB, 2, Bl0);
    VM0;                       PACKB(praw1, Bl1); LGBAR; STEPM(accB, 3, Bl1);

#undef LOADB
#undef PACKB
#undef STEPM

    // ---- epilogues: bias + relu + store + row max (atomic), both b's ----
#define EPI(BI, ACC) {                                                        \
    float* zb = z + (size_t)(BI) * COUT * HW;                                 \
    _Pragma("unroll") for (int mf = 0; mf < 2; ++mf) {                        \
        int obase = o0 + wm + mf * 16 + l4 * 4;                               \
        float bb0 = b2[obase + 0], bb1 = b2[obase + 1];                       \
        float bb2v = b2[obase + 2], bb3 = b2[obase + 3];                      \
        float rmax[4] = {0.f, 0.f, 0.f, 0.f};                                 \
        _Pragma("unroll") for (int nf = 0; nf < 4; ++nf) {                    \
            int n = n0 + wn + nf * 16 + l15;                                  \
            bool valid = (n < HW);                                            \
            float v0 = fmaxf(ACC[mf][nf][0] + bb0, 0.f);                      \
            float v1 = fmaxf(ACC[mf][nf][1] + bb1, 0.f);                      \
            float v2 = fmaxf(ACC[mf][nf][2] + bb2v, 0.f);                     \
            float v3 = fmaxf(ACC[mf][nf][3] + bb3, 0.f);                      \
            if (valid) {                                                      \
                zb[(size_t)(obase + 0) * HW + n] = v0;                        \
                zb[(size_t)(obase + 1) * HW + n] = v1;                        \
                zb[(size_t)(obase + 2) * HW + n] = v2;                        \
                zb[(size_t)(obase + 3) * HW + n] = v3;                        \
                rmax[0] = fmaxf(rmax[0], v0);                                 \
                rmax[1] = fmaxf(rmax[1], v1);                                 \
                rmax[2] = fmaxf(rmax[2], v2);                                 \
                rmax[3] = fmaxf(rmax[3], v3);                                 \
            }                                                                 \
        }                                                                     \
        _Pragma("unroll") for (int r = 0; r < 4; ++r) {                       \
            float v = rmax[r];                                                \
            v = fmaxf(v, __shfl_xor(v, 1, 64));                               \
            v = fmaxf(v, __shfl_xor(v, 2, 64));                               \
            v = fmaxf(v, __shfl_xor(v, 4, 64));                               \
            v = fmaxf(v, __shfl_xor(v, 8, 64));                               \
            if (l15 == 0)                                                     \
                atomicMax(&pwmax[(BI) * COUT + obase + r], __float_as_uint(v)); \
        }                                                                     \
    } }

    EPI(b0, accA);
    EPI(b1, accB);
#undef EPI
}

// ---------------- K3: apply pointwise cut ---------------------------------
__global__ __launch_bounds__(256) void cut_kernel(const unsigned* __restrict__ pwmax,
                                                  float* __restrict__ z) {
    int base = blockIdx.x * 8;
#pragma unroll
    for (int j = 0; j < 8; ++j) {
        int bo = base + j;
        if (__uint_as_float(pwmax[bo]) >= 1e-3f) continue;
        float4* zp = (float4*)(z + (size_t)bo * HW);
        for (int i = threadIdx.x; i < HW / 4; i += 256)
            zp[i] = make_float4(0.f, 0.f, 0.f, 0.f);
    }
}

extern "C" void kernel_launch(void* const* d_in, const int* in_sizes, int n_in,
                              void* d_out, int out_size, void* d_ws, size_t ws_size,
                              hipStream_t stream) {
    const float* x   = (const float*)d_in[0];
    const float* dww = (const float*)d_in[1];
    const float* dwb = (const float*)d_in[2];
    const float* g1  = (const float*)d_in[3];
    const float* be1 = (const float*)d_in[4];
    const float* mu1 = (const float*)d_in[5];
    const float* va1 = (const float*)d_in[6];
    const float* pww = (const float*)d_in[7];
    const float* pwb = (const float*)d_in[8];
    const float* g2  = (const float*)d_in[9];
    const float* be2 = (const float*)d_in[10];
    const float* mu2 = (const float*)d_in[11];
    const float* va2 = (const float*)d_in[12];
    float* z = (float*)d_out;

    char* ws = (char*)d_ws;
    const size_t Y_BYTES = (size_t)BATCH * CIN * NPAD * 2;  // 52,428,800
    unsigned short* y  = (unsigned short*)ws;
    unsigned short* Wp = (unsigned short*)(ws + Y_BYTES);
    float* b2          = (float*)(ws + Y_BYTES + 131072);
    unsigned* pwmax    = (unsigned*)(ws + Y_BYTES + 131072 + 1024);

    prep_kernel<<<256, 256, 0, stream>>>(pww, pwb, g2, be2, mu2, va2, Wp, b2, pwmax);
    dw_kernel<<<2048, 256, 0, stream>>>(x, dww, dwb, g1, be1, mu1, va1, y);
    pw_kernel<<<1600, 256, 0, stream>>>(y, Wp, b2, z, pwmax);
    cut_kernel<<<BATCH * COUT / 8, 256, 0, stream>>>(pwmax, z);
}